// Round 5
// baseline (259.786 us; speedup 1.0000x reference)
//
#include <hip/hip_runtime.h>
#include <hip/hip_bf16.h>

// Problem constants (B=4, T=2048, C=1024, NH=16, HD=64)
// fp32 in, fp32 out, bf16 MFMA compute internally.
#define B_SZ 4
#define T_SZ 2048
#define C_SZ 1024
#define NH_SZ 16
#define HD_SZ 64
#define M_SZ (B_SZ * T_SZ)  // 8192 rows

typedef __bf16 bf16x8 __attribute__((ext_vector_type(8)));
typedef __bf16 bf16x4 __attribute__((ext_vector_type(4)));
typedef float f32x4 __attribute__((ext_vector_type(4)));

// async global->LDS, 16B per lane. LDS dest is wave-uniform base + lane*16.
__device__ __forceinline__ void async_ld16(__hip_bfloat16* lds, const __hip_bfloat16* g) {
  __builtin_amdgcn_global_load_lds(
      (const __attribute__((address_space(1))) void*)g,
      (__attribute__((address_space(3))) void*)lds, 16, 0, 0);
}

// raw block barrier; compiler memory fences on both sides, no forced drain.
__device__ __forceinline__ void bar() {
  asm volatile("" ::: "memory");
  __builtin_amdgcn_s_barrier();
  asm volatile("" ::: "memory");
}

// Swizzled LDS fragment read for 64B rows (BK=32):
// physical byte = 64*row + 16*(quad ^ ((row>>1)&3)).
__device__ __forceinline__ bf16x8 frag32(const __hip_bfloat16* base, int row, int q) {
  const int byte = (row << 6) + (((q ^ (row >> 1)) & 3) << 4);
  return *(const bf16x8*)((const char*)base + byte);
}

// pack two f32 -> dword of 2 bf16 (lo = first arg), hardware RNE cvt.
// T12 recipe: no builtin on gfx950; non-volatile asm so it can schedule.
__device__ __forceinline__ uint32_t pk2(float lo, float hi) {
  uint32_t r;
  asm("v_cvt_pk_bf16_f32 %0, %1, %2" : "=v"(r) : "v"(lo), "v"(hi));
  return r;
}

// ---------------------------------------------------------------------------
// Pre-pass 1: fp32 -> bf16 copy (x -> xb).
// ---------------------------------------------------------------------------
__global__ __launch_bounds__(256) void conv_bf16_kernel(
    const float* __restrict__ X, __hip_bfloat16* __restrict__ Y) {
  const int i = (blockIdx.x * 256 + threadIdx.x) * 4;
  float4 v = *(const float4*)&X[i];
  union { bf16x4 v; __hip_bfloat16 h[4]; } o;
  o.h[0] = __float2bfloat16(v.x); o.h[1] = __float2bfloat16(v.y);
  o.h[2] = __float2bfloat16(v.z); o.h[3] = __float2bfloat16(v.w);
  *(bf16x4*)&Y[i] = o.v;
}

// ---------------------------------------------------------------------------
// Pre-pass 2: Wt[n][k] = bf16(W[k][n]); W is [KD][ND] fp32. 32x32 LDS tiles.
// ---------------------------------------------------------------------------
template <int KD, int ND>
__global__ __launch_bounds__(256) void transpose_conv_kernel(
    const float* __restrict__ W, __hip_bfloat16* __restrict__ Wt) {
  __shared__ float sT[32][33];
  const int n0 = blockIdx.x * 32, k0 = blockIdx.y * 32;
  const int tid = threadIdx.x;
  {
    const int r = tid >> 3, c = (tid & 7) * 4;
    float4 v = *(const float4*)&W[(size_t)(k0 + r) * ND + n0 + c];
    sT[r][c] = v.x; sT[r][c + 1] = v.y; sT[r][c + 2] = v.z; sT[r][c + 3] = v.w;
  }
  __syncthreads();
  {
    const int n = tid >> 3, kq = (tid & 7) * 4;
    union { bf16x4 v; __hip_bfloat16 h[4]; } o;
#pragma unroll
    for (int j = 0; j < 4; ++j) o.h[j] = __float2bfloat16(sT[kq + j][n]);
    *(bf16x4*)&Wt[(size_t)(n0 + n) * KD + k0 + kq] = o.v;
  }
}

// ---------------------------------------------------------------------------
// Triple-buffered, never-drain GEMM kernels (BK=32). Verified r3/r4.
// ---------------------------------------------------------------------------

// Q scale folds softmax 1/sqrt(64) AND log2(e) so attention can use exp2:
// 0.125 * 1.4426950408889634
#define Q_PRESCALE 0.18033688011112042f

// 256x256 tile, 8 waves (2Mx4N). Covers Q+K columns (N=2048): grid 256.
__global__ __launch_bounds__(512, 2) void gemm_tri256_qk(
    const __hip_bfloat16* __restrict__ A, const __hip_bfloat16* __restrict__ Bt,
    const float* __restrict__ bias,
    __hip_bfloat16* __restrict__ qR, __hip_bfloat16* __restrict__ kR) {
  __shared__ __align__(16) __hip_bfloat16 sA[3][256 * 32];  // 48 KiB
  __shared__ __align__(16) __hip_bfloat16 sB[3][256 * 32];  // 48 KiB

  const int tid = threadIdx.x;
  const int wave = tid >> 6, lane = tid & 63;
  const int quad = lane >> 4, l16 = lane & 15;
  const int wm = wave >> 2, wn = wave & 3;

  const int xcd = (int)blockIdx.x & 7, lb = (int)blockIdx.x >> 3;
  const int bm = (xcd * 4 + (lb >> 3)) * 256;
  const int bn = (lb & 7) * 256;

  const int srow = tid >> 2;
  const int scol = 8 * ((tid & 3) ^ ((tid >> 3) & 3));
  const int sdst = tid * 8;  // elems
  const __hip_bfloat16* gA = A + (size_t)(bm + srow) * C_SZ + scol;
  const __hip_bfloat16* gB = Bt + (size_t)(bn + srow) * C_SZ + scol;

  f32x4 acc[8][4];
#pragma unroll
  for (int m = 0; m < 8; ++m)
#pragma unroll
    for (int n = 0; n < 4; ++n) acc[m][n] = (f32x4){0.f, 0.f, 0.f, 0.f};

#define STG256(buf, kt)                                                         \
  do {                                                                          \
    async_ld16(&sA[buf][sdst], gA + (kt) * 32);                                 \
    async_ld16(&sA[buf][4096 + sdst], gA + (size_t)128 * C_SZ + (kt) * 32);     \
    async_ld16(&sB[buf][sdst], gB + (kt) * 32);                                 \
    async_ld16(&sB[buf][4096 + sdst], gB + (size_t)128 * C_SZ + (kt) * 32);     \
  } while (0)

  STG256(0, 0);
  STG256(1, 1);
  asm volatile("s_waitcnt vmcnt(4)" ::: "memory");
  bar();

  constexpr int NT = C_SZ / 32;  // 32
  int cur = 0;
  for (int kt = 0; kt < NT; ++kt) {
    const int stg = cur == 0 ? 2 : cur - 1;  // (cur+2)%3
    if (kt + 2 < NT) STG256(stg, kt + 2);

    const __hip_bfloat16* ab = sA[cur];
    const __hip_bfloat16* bb = sB[cur];
    bf16x8 af[8], bfr[4];
#pragma unroll
    for (int mq = 0; mq < 8; ++mq) af[mq] = frag32(ab, wm * 128 + mq * 16 + l16, quad);
#pragma unroll
    for (int nq = 0; nq < 4; ++nq) bfr[nq] = frag32(bb, wn * 64 + nq * 16 + l16, quad);
#pragma unroll
    for (int mq = 0; mq < 8; ++mq)
#pragma unroll
      for (int nq = 0; nq < 4; ++nq)
        acc[mq][nq] = __builtin_amdgcn_mfma_f32_16x16x32_bf16(af[mq], bfr[nq], acc[mq][nq], 0, 0, 0);

    if (kt + 1 < NT) {
      if (kt + 2 < NT) asm volatile("s_waitcnt vmcnt(4)" ::: "memory");
      else             asm volatile("s_waitcnt vmcnt(0)" ::: "memory");
      bar();
    }
    cur = cur == 2 ? 0 : cur + 1;
  }
#undef STG256

  float bv[4];
#pragma unroll
  for (int nq = 0; nq < 4; ++nq) bv[nq] = bias[bn + wn * 64 + nq * 16 + l16];
  const bool isQ = bn < C_SZ;
#pragma unroll
  for (int mq = 0; mq < 8; ++mq)
#pragma unroll
    for (int nq = 0; nq < 4; ++nq) {
      const int col = bn + wn * 64 + nq * 16 + l16;
      const int hh = (col >> 6) & 15, d = col & 63;
#pragma unroll
      for (int r = 0; r < 4; ++r) {
        const int row = bm + wm * 128 + mq * 16 + quad * 4 + r;
        const int bb_ = row >> 11, t = row & 2047;
        const size_t idx = ((size_t)(bb_ * 16 + hh) * T_SZ + t) * HD_SZ + d;
        const float val = acc[mq][nq][r] + bv[nq];
        if (isQ) qR[idx] = __float2bfloat16(val * Q_PRESCALE);
        else     kR[idx] = __float2bfloat16(val);
      }
    }
}

// 128x128 tile, 4 waves. MODE 0: V cols -> vT [bh][d][t]; MODE 1: proj -> fp32.
template <int MODE>
__global__ __launch_bounds__(256, 3) void gemm_tri128(
    const __hip_bfloat16* __restrict__ A, const __hip_bfloat16* __restrict__ Bt,
    const float* __restrict__ bias, float* __restrict__ Cf,
    __hip_bfloat16* __restrict__ vT) {
  __shared__ __align__(16) __hip_bfloat16 sA[3][128 * 32];  // 24 KiB
  __shared__ __align__(16) __hip_bfloat16 sB[3][128 * 32];  // 24 KiB

  const int tid = threadIdx.x;
  const int wave = tid >> 6, lane = tid & 63;
  const int quad = lane >> 4, l16 = lane & 15;
  const int rw = (wave & 1) * 64, cw = (wave >> 1) * 64;

  const int xcd = (int)blockIdx.x & 7, lb = (int)blockIdx.x >> 3;
  const int bm = (xcd * 8 + (lb >> 3)) * 128;
  const int bn = (lb & 7) * 128;

  const int srow = tid >> 2;  // 0..63
  const int scol = 8 * ((tid & 3) ^ ((tid >> 3) & 3));
  const int sdst = tid * 8;
  const __hip_bfloat16* gA = A + (size_t)(bm + srow) * C_SZ + scol;
  const __hip_bfloat16* gB = Bt + (size_t)(bn + srow) * C_SZ + scol;

  f32x4 acc[4][4];
#pragma unroll
  for (int i = 0; i < 4; ++i)
#pragma unroll
    for (int j = 0; j < 4; ++j) acc[i][j] = (f32x4){0.f, 0.f, 0.f, 0.f};

#define STG128(buf, kt)                                                        \
  do {                                                                         \
    async_ld16(&sA[buf][sdst], gA + (kt) * 32);                                \
    async_ld16(&sA[buf][2048 + sdst], gA + (size_t)64 * C_SZ + (kt) * 32);     \
    async_ld16(&sB[buf][sdst], gB + (kt) * 32);                                \
    async_ld16(&sB[buf][2048 + sdst], gB + (size_t)64 * C_SZ + (kt) * 32);     \
  } while (0)

  STG128(0, 0);
  STG128(1, 1);
  asm volatile("s_waitcnt vmcnt(4)" ::: "memory");
  bar();

  constexpr int NT = C_SZ / 32;  // 32
  int cur = 0;
  for (int kt = 0; kt < NT; ++kt) {
    const int stg = cur == 0 ? 2 : cur - 1;
    if (kt + 2 < NT) STG128(stg, kt + 2);

    const __hip_bfloat16* ab = sA[cur];
    const __hip_bfloat16* bb = sB[cur];
    bf16x8 af[4], bfr[4];
#pragma unroll
    for (int mq = 0; mq < 4; ++mq) af[mq] = frag32(ab, rw + mq * 16 + l16, quad);
#pragma unroll
    for (int nq = 0; nq < 4; ++nq) bfr[nq] = frag32(bb, cw + nq * 16 + l16, quad);
#pragma unroll
    for (int mq = 0; mq < 4; ++mq)
#pragma unroll
      for (int nq = 0; nq < 4; ++nq)
        acc[mq][nq] = __builtin_amdgcn_mfma_f32_16x16x32_bf16(af[mq], bfr[nq], acc[mq][nq], 0, 0, 0);

    if (kt + 1 < NT) {
      if (kt + 2 < NT) asm volatile("s_waitcnt vmcnt(4)" ::: "memory");
      else             asm volatile("s_waitcnt vmcnt(0)" ::: "memory");
      bar();
    }
    cur = cur == 2 ? 0 : cur + 1;
  }
#undef STG128

  float bv[4];
#pragma unroll
  for (int nq = 0; nq < 4; ++nq) bv[nq] = bias[bn + cw + nq * 16 + l16];
#pragma unroll
  for (int mq = 0; mq < 4; ++mq)
#pragma unroll
    for (int nq = 0; nq < 4; ++nq) {
      const int col = bn + cw + nq * 16 + l16;  // 0..1023 local
#pragma unroll
      for (int r = 0; r < 4; ++r) {
        const int row = bm + rw + mq * 16 + quad * 4 + r;
        const float val = acc[mq][nq][r] + bv[nq];
        if (MODE == 0) {
          const int bb_ = row >> 11, t = row & 2047;
          const int hh = col >> 6, d = col & 63;
          vT[((size_t)(bb_ * 16 + hh) * HD_SZ + d) * T_SZ + t] = __float2bfloat16(val);
        } else {
          Cf[(size_t)row * C_SZ + col] = val;
        }
      }
    }
}

// ---------------------------------------------------------------------------
// MFMA causal flash attention, r5: swapped QK^T + in-register P exchange
// (verified r4) + hw v_cvt_pk_bf16_f32 pack + T5 setprio around MFMA
// clusters + 5 blocks/CU (VGPR 48, LDS 27.6 KB both allow it).
// ---------------------------------------------------------------------------
#define ATT_ST 72

__global__ __launch_bounds__(256, 5) void attn_mfma_kernel(
    const __hip_bfloat16* __restrict__ qR, const __hip_bfloat16* __restrict__ kR,
    const __hip_bfloat16* __restrict__ vT, __hip_bfloat16* __restrict__ y) {
  __shared__ __align__(16) __hip_bfloat16 sQ[64][ATT_ST];
  __shared__ __align__(16) __hip_bfloat16 sK[64][ATT_ST];
  __shared__ __align__(16) __hip_bfloat16 sVt[64][ATT_ST];  // [dim][key]

  const int bh = blockIdx.x;                         // XCD = bh%8 (heuristic)
  const int tile = (int)gridDim.y - 1 - blockIdx.y;  // longest-first
  const int t0 = tile * 64;
  const int tid = threadIdx.x;
  const int wave = tid >> 6, lane = tid & 63;
  const int quad = lane >> 4, l16 = lane & 15;
  const int wrow0 = wave * 16;

  const __hip_bfloat16* qb = qR + (size_t)bh * T_SZ * HD_SZ;
  const __hip_bfloat16* kb = kR + (size_t)bh * T_SZ * HD_SZ;
  const __hip_bfloat16* vb = vT + (size_t)bh * HD_SZ * T_SZ;

  const int sr = tid >> 2, sc = (tid & 3) * 16;  // 16 elems/thread per 4K tile

  // exchange constants (derived 8-shfl schedule; verified r4)
  const bool uSel = (quad & 1) != 0;
  const bool cSel = (quad >> 1) != 0;
  const int srcE = l16 + 32 * (quad & 1) + 16 * (quad >> 1);
  const int srcO = srcE ^ 16;

  // ---- stage Q (contiguous 8 KB) ----
  {
    const __hip_bfloat16* src = qb + (size_t)t0 * HD_SZ + tid * 16;
    *(float4*)&sQ[sr][sc] = *(const float4*)src;
    *(float4*)&sQ[sr][sc + 8] = *(const float4*)(src + 8);
  }

  // ---- preload chunk 0 K/V into regs (coalesced) ----
  float4 krg0, krg1, vrg0, vrg1;
  {
    const __hip_bfloat16* ks = kb + tid * 16;  // j0 = 0
    krg0 = *(const float4*)ks;
    krg1 = *(const float4*)(ks + 8);
    const __hip_bfloat16* vs = vb + (size_t)sr * T_SZ + sc;  // row d, cols t
    vrg0 = *(const float4*)vs;
    vrg1 = *(const float4*)(vs + 8);
  }

  __syncthreads();  // Q visible
  bf16x8 qa0 = *(const bf16x8*)&sQ[wrow0 + l16][quad * 8];
  bf16x8 qa1 = *(const bf16x8*)&sQ[wrow0 + l16][32 + quad * 8];

  float lacc = 0.f;  // row-sum partial for q = wrow0+l16 (own-quad key classes)
  f32x4 o[4];
#pragma unroll
  for (int nn = 0; nn < 4; ++nn) o[nn] = (f32x4){0.f, 0.f, 0.f, 0.f};

  for (int j0 = 0; j0 <= t0; j0 += 64) {
    // ---- drain prefetch regs -> LDS ----
    *(float4*)&sK[sr][sc] = krg0;
    *(float4*)&sK[sr][sc + 8] = krg1;
    *(float4*)&sVt[sr][sc] = vrg0;
    *(float4*)&sVt[sr][sc + 8] = vrg1;
    // ---- issue next chunk's loads (overlap with compute below) ----
    if (j0 + 64 <= t0) {
      const __hip_bfloat16* ks = kb + (size_t)(j0 + 64) * HD_SZ + tid * 16;
      krg0 = *(const float4*)ks;
      krg1 = *(const float4*)(ks + 8);
      const __hip_bfloat16* vs = vb + (size_t)sr * T_SZ + j0 + 64 + sc;
      vrg0 = *(const float4*)vs;
      vrg1 = *(const float4*)(vs + 8);
    }
    __syncthreads();  // K/V visible

    // ---- S^T = K.Q^T : lane holds S[q=wrow0+l16][key=16*sub+4*quad+r] ----
    f32x4 s[4];
    __builtin_amdgcn_s_setprio(1);
#pragma unroll
    for (int sub = 0; sub < 4; ++sub) {
      s[sub] = (f32x4){0.f, 0.f, 0.f, 0.f};
      bf16x8 kf0 = *(const bf16x8*)&sK[sub * 16 + l16][quad * 8];
      s[sub] = __builtin_amdgcn_mfma_f32_16x16x32_bf16(kf0, qa0, s[sub], 0, 0, 0);
      bf16x8 kf1 = *(const bf16x8*)&sK[sub * 16 + l16][32 + quad * 8];
      s[sub] = __builtin_amdgcn_mfma_f32_16x16x32_bf16(kf1, qa1, s[sub], 0, 0, 0);
    }
    __builtin_amdgcn_s_setprio(0);

    // ---- causal mask (diagonal chunk only) ----
    if (j0 == t0) {
      const int qrow = wrow0 + l16;
#pragma unroll
      for (int sub = 0; sub < 4; ++sub)
#pragma unroll
        for (int r = 0; r < 4; ++r)
          if (sub * 16 + quad * 4 + r > qrow) s[sub][r] = -1e30f;
    }

    // ---- p = exp2(s) (scale pre-folded); row-sum partial ----
#pragma unroll
    for (int sub = 0; sub < 4; ++sub)
#pragma unroll
      for (int r = 0; r < 4; ++r) s[sub][r] = __builtin_amdgcn_exp2f(s[sub][r]);
#pragma unroll
    for (int sub = 0; sub < 4; ++sub)
      lacc += (s[sub][0] + s[sub][1]) + (s[sub][2] + s[sub][3]);

    // ---- pack to bf16 dwords (hw cvt_pk): pk[sub][h] = keys 16sub+4quad+2h,+1
    uint32_t pk[4][2];
#pragma unroll
    for (int sub = 0; sub < 4; ++sub)
#pragma unroll
      for (int h = 0; h < 2; ++h)
        pk[sub][h] = pk2(s[sub][2 * h], s[sub][2 * h + 1]);

    // ---- 8-shfl quad exchange -> PV A-frags (keys quad*8+j / 32+quad*8+j) --
    uint32_t g0 = (uint32_t)__shfl((int)(uSel ? pk[1][0] : pk[0][0]), srcE, 64);
    uint32_t g1 = (uint32_t)__shfl((int)(uSel ? pk[0][0] : pk[1][0]), srcO, 64);
    uint32_t g2 = (uint32_t)__shfl((int)(uSel ? pk[3][0] : pk[2][0]), srcE, 64);
    uint32_t g3 = (uint32_t)__shfl((int)(uSel ? pk[2][0] : pk[3][0]), srcO, 64);
    uint32_t g4 = (uint32_t)__shfl((int)(uSel ? pk[1][1] : pk[0][1]), srcE, 64);
    uint32_t g5 = (uint32_t)__shfl((int)(uSel ? pk[0][1] : pk[1][1]), srcO, 64);
    uint32_t g6 = (uint32_t)__shfl((int)(uSel ? pk[3][1] : pk[2][1]), srcE, 64);
    uint32_t g7 = (uint32_t)__shfl((int)(uSel ? pk[2][1] : pk[3][1]), srcO, 64);

    union PU { uint32_t d[4]; bf16x8 v; };
    PU A0, A1;
    A0.d[0] = cSel ? g1 : g0;  A0.d[1] = cSel ? g5 : g4;
    A0.d[2] = cSel ? g0 : g1;  A0.d[3] = cSel ? g4 : g5;
    A1.d[0] = cSel ? g3 : g2;  A1.d[1] = cSel ? g7 : g6;
    A1.d[2] = cSel ? g2 : g3;  A1.d[3] = cSel ? g6 : g7;

    // ---- O += P.V ----
    __builtin_amdgcn_s_setprio(1);
#pragma unroll
    for (int nn = 0; nn < 4; ++nn) {
      bf16x8 vf0 = *(const bf16x8*)&sVt[nn * 16 + l16][quad * 8];
      o[nn] = __builtin_amdgcn_mfma_f32_16x16x32_bf16(A0.v, vf0, o[nn], 0, 0, 0);
      bf16x8 vf1 = *(const bf16x8*)&sVt[nn * 16 + l16][32 + quad * 8];
      o[nn] = __builtin_amdgcn_mfma_f32_16x16x32_bf16(A1.v, vf1, o[nn], 0, 0, 0);
    }
    __builtin_amdgcn_s_setprio(0);

    if (j0 < t0) __syncthreads();  // readers done before next overwrite
  }

  // ---- final row-sum reduction + epilogue ----
  lacc += __shfl_xor(lacc, 16);
  lacc += __shfl_xor(lacc, 32);
  // o[nn][r] belongs to q = wrow0+quad*4+r; its row-sum lives at l16'=quad*4+r
  float inv[4];
#pragma unroll
  for (int r = 0; r < 4; ++r)
    inv[r] = 1.0f / __shfl(lacc, (lane & 48) + quad * 4 + r, 64);

  const int b = bh >> 4, h = bh & 15;
#pragma unroll
  for (int nn = 0; nn < 4; ++nn)
#pragma unroll
    for (int r = 0; r < 4; ++r) {
      const int t = t0 + wrow0 + quad * 4 + r;
      y[((size_t)b * T_SZ + t) * C_SZ + h * HD_SZ + nn * 16 + l16] =
          __float2bfloat16(o[nn][r] * inv[r]);
    }
}

// ---------------------------------------------------------------------------
extern "C" void kernel_launch(void* const* d_in, const int* in_sizes, int n_in,
                              void* d_out, int out_size, void* d_ws, size_t ws_size,
                              hipStream_t stream) {
  const float* x      = (const float*)d_in[0];  // [8192,1024] fp32
  const float* w_attn = (const float*)d_in[1];  // [1024,3072] fp32
  const float* b_attn = (const float*)d_in[2];  // [3072] fp32
  const float* w_proj = (const float*)d_in[3];  // [1024,1024] fp32
  const float* b_proj = (const float*)d_in[4];  // [1024] fp32
  float* out = (float*)d_out;                   // [8192,1024] fp32

  // ws layout (75.5 MB): xb | waT | wpT | qR | kR | vT ; yb aliases xb.
  __hip_bfloat16* xb  = (__hip_bfloat16*)d_ws;                    // 16.78 MB
  __hip_bfloat16* waT = xb + (size_t)M_SZ * C_SZ;                 //  6.29 MB
  __hip_bfloat16* wpT = waT + (size_t)3 * C_SZ * C_SZ;            //  2.10 MB
  __hip_bfloat16* qR  = wpT + (size_t)C_SZ * C_SZ;                // 16.78 MB
  __hip_bfloat16* kR  = qR + (size_t)M_SZ * C_SZ;                 // 16.78 MB
  __hip_bfloat16* vT  = kR + (size_t)M_SZ * C_SZ;                 // 16.78 MB
  __hip_bfloat16* yb  = xb;  // xb dead after QKV GEMMs

  conv_bf16_kernel<<<(M_SZ * C_SZ) / (256 * 4), 256, 0, stream>>>(x, xb);
  transpose_conv_kernel<C_SZ, 3 * C_SZ><<<dim3(96, 32), 256, 0, stream>>>(w_attn, waT);
  transpose_conv_kernel<C_SZ, C_SZ><<<dim3(32, 32), 256, 0, stream>>>(w_proj, wpT);

  // 1a) Q+K projection: 256^2 triple-buffer, grid 256 = 1 exact round.
  gemm_tri256_qk<<<dim3(256), 512, 0, stream>>>(xb, waT, b_attn, qR, kR);

  // 1b) V projection: 128^2 triple-buffer, 3 blk/CU, grid 512 co-resident.
  gemm_tri128<0><<<dim3(512), 256, 0, stream>>>(
      xb, waT + (size_t)2 * C_SZ * C_SZ, b_attn + 2 * C_SZ, nullptr, vT);

  // 2) causal flash attention
  attn_mfma_kernel<<<dim3(B_SZ * NH_SZ, T_SZ / 64), 256, 0, stream>>>(qR, kR, vT, yb);

  // 3) output projection -> fp32 out
  gemm_tri128<1><<<dim3(512), 256, 0, stream>>>(
      (const __hip_bfloat16*)yb, wpT, b_proj, out, nullptr);
}

// Round 6
// 249.824 us; speedup vs baseline: 1.0399x; 1.0399x over previous
//
#include <hip/hip_runtime.h>
#include <hip/hip_bf16.h>

// Problem constants (B=4, T=2048, C=1024, NH=16, HD=64)
// fp32 in, fp32 out, bf16 MFMA compute internally.
#define B_SZ 4
#define T_SZ 2048
#define C_SZ 1024
#define NH_SZ 16
#define HD_SZ 64
#define M_SZ (B_SZ * T_SZ)  // 8192 rows

typedef __bf16 bf16x8 __attribute__((ext_vector_type(8)));
typedef __bf16 bf16x4 __attribute__((ext_vector_type(4)));
typedef float f32x4 __attribute__((ext_vector_type(4)));

// async global->LDS, 16B per lane. LDS dest is wave-uniform base + lane*16.
__device__ __forceinline__ void async_ld16(__hip_bfloat16* lds, const __hip_bfloat16* g) {
  __builtin_amdgcn_global_load_lds(
      (const __attribute__((address_space(1))) void*)g,
      (__attribute__((address_space(3))) void*)lds, 16, 0, 0);
}

// raw block barrier; compiler memory fences on both sides, no forced drain.
__device__ __forceinline__ void bar() {
  asm volatile("" ::: "memory");
  __builtin_amdgcn_s_barrier();
  asm volatile("" ::: "memory");
}

// Swizzled LDS fragment read for 64B rows (BK=32):
// physical byte = 64*row + 16*(quad ^ ((row>>1)&3)).
__device__ __forceinline__ bf16x8 frag32(const __hip_bfloat16* base, int row, int q) {
  const int byte = (row << 6) + (((q ^ (row >> 1)) & 3) << 4);
  return *(const bf16x8*)((const char*)base + byte);
}

// pack two f32 -> dword of 2 bf16 (lo = first arg), hardware RNE cvt.
__device__ __forceinline__ uint32_t pk2(float lo, float hi) {
  uint32_t r;
  asm("v_cvt_pk_bf16_f32 %0, %1, %2" : "=v"(r) : "v"(lo), "v"(hi));
  return r;
}

// ---------------------------------------------------------------------------
// Pre-pass 1: fp32 -> bf16 copy (x -> xb).
// ---------------------------------------------------------------------------
__global__ __launch_bounds__(256) void conv_bf16_kernel(
    const float* __restrict__ X, __hip_bfloat16* __restrict__ Y) {
  const int i = (blockIdx.x * 256 + threadIdx.x) * 4;
  float4 v = *(const float4*)&X[i];
  union { bf16x4 v; __hip_bfloat16 h[4]; } o;
  o.h[0] = __float2bfloat16(v.x); o.h[1] = __float2bfloat16(v.y);
  o.h[2] = __float2bfloat16(v.z); o.h[3] = __float2bfloat16(v.w);
  *(bf16x4*)&Y[i] = o.v;
}

// ---------------------------------------------------------------------------
// Pre-pass 2: Wt[n][k] = bf16(W[k][n]); W is [KD][ND] fp32. 32x32 LDS tiles.
// ---------------------------------------------------------------------------
template <int KD, int ND>
__global__ __launch_bounds__(256) void transpose_conv_kernel(
    const float* __restrict__ W, __hip_bfloat16* __restrict__ Wt) {
  __shared__ float sT[32][33];
  const int n0 = blockIdx.x * 32, k0 = blockIdx.y * 32;
  const int tid = threadIdx.x;
  {
    const int r = tid >> 3, c = (tid & 7) * 4;
    float4 v = *(const float4*)&W[(size_t)(k0 + r) * ND + n0 + c];
    sT[r][c] = v.x; sT[r][c + 1] = v.y; sT[r][c + 2] = v.z; sT[r][c + 3] = v.w;
  }
  __syncthreads();
  {
    const int n = tid >> 3, kq = (tid & 7) * 4;
    union { bf16x4 v; __hip_bfloat16 h[4]; } o;
#pragma unroll
    for (int j = 0; j < 4; ++j) o.h[j] = __float2bfloat16(sT[kq + j][n]);
    *(bf16x4*)&Wt[(size_t)(n0 + n) * KD + k0 + kq] = o.v;
  }
}

// ---------------------------------------------------------------------------
// Triple-buffered, never-drain GEMM kernels (BK=32). Verified r3/r4/r5.
// ---------------------------------------------------------------------------

// Q scale folds softmax 1/sqrt(64) AND log2(e) so attention can use exp2:
// 0.125 * 1.4426950408889634
#define Q_PRESCALE 0.18033688011112042f

// 256x256 tile, 8 waves (2Mx4N). Covers Q+K columns (N=2048): grid 256.
__global__ __launch_bounds__(512, 2) void gemm_tri256_qk(
    const __hip_bfloat16* __restrict__ A, const __hip_bfloat16* __restrict__ Bt,
    const float* __restrict__ bias,
    __hip_bfloat16* __restrict__ qR, __hip_bfloat16* __restrict__ kR) {
  __shared__ __align__(16) __hip_bfloat16 sA[3][256 * 32];  // 48 KiB
  __shared__ __align__(16) __hip_bfloat16 sB[3][256 * 32];  // 48 KiB

  const int tid = threadIdx.x;
  const int wave = tid >> 6, lane = tid & 63;
  const int quad = lane >> 4, l16 = lane & 15;
  const int wm = wave >> 2, wn = wave & 3;

  const int xcd = (int)blockIdx.x & 7, lb = (int)blockIdx.x >> 3;
  const int bm = (xcd * 4 + (lb >> 3)) * 256;
  const int bn = (lb & 7) * 256;

  const int srow = tid >> 2;
  const int scol = 8 * ((tid & 3) ^ ((tid >> 3) & 3));
  const int sdst = tid * 8;  // elems
  const __hip_bfloat16* gA = A + (size_t)(bm + srow) * C_SZ + scol;
  const __hip_bfloat16* gB = Bt + (size_t)(bn + srow) * C_SZ + scol;

  f32x4 acc[8][4];
#pragma unroll
  for (int m = 0; m < 8; ++m)
#pragma unroll
    for (int n = 0; n < 4; ++n) acc[m][n] = (f32x4){0.f, 0.f, 0.f, 0.f};

#define STG256(buf, kt)                                                         \
  do {                                                                          \
    async_ld16(&sA[buf][sdst], gA + (kt) * 32);                                 \
    async_ld16(&sA[buf][4096 + sdst], gA + (size_t)128 * C_SZ + (kt) * 32);     \
    async_ld16(&sB[buf][sdst], gB + (kt) * 32);                                 \
    async_ld16(&sB[buf][4096 + sdst], gB + (size_t)128 * C_SZ + (kt) * 32);     \
  } while (0)

  STG256(0, 0);
  STG256(1, 1);
  asm volatile("s_waitcnt vmcnt(4)" ::: "memory");
  bar();

  constexpr int NT = C_SZ / 32;  // 32
  int cur = 0;
  for (int kt = 0; kt < NT; ++kt) {
    const int stg = cur == 0 ? 2 : cur - 1;  // (cur+2)%3
    if (kt + 2 < NT) STG256(stg, kt + 2);

    const __hip_bfloat16* ab = sA[cur];
    const __hip_bfloat16* bb = sB[cur];
    bf16x8 af[8], bfr[4];
#pragma unroll
    for (int mq = 0; mq < 8; ++mq) af[mq] = frag32(ab, wm * 128 + mq * 16 + l16, quad);
#pragma unroll
    for (int nq = 0; nq < 4; ++nq) bfr[nq] = frag32(bb, wn * 64 + nq * 16 + l16, quad);
#pragma unroll
    for (int mq = 0; mq < 8; ++mq)
#pragma unroll
      for (int nq = 0; nq < 4; ++nq)
        acc[mq][nq] = __builtin_amdgcn_mfma_f32_16x16x32_bf16(af[mq], bfr[nq], acc[mq][nq], 0, 0, 0);

    if (kt + 1 < NT) {
      if (kt + 2 < NT) asm volatile("s_waitcnt vmcnt(4)" ::: "memory");
      else             asm volatile("s_waitcnt vmcnt(0)" ::: "memory");
      bar();
    }
    cur = cur == 2 ? 0 : cur + 1;
  }
#undef STG256

  float bv[4];
#pragma unroll
  for (int nq = 0; nq < 4; ++nq) bv[nq] = bias[bn + wn * 64 + nq * 16 + l16];
  const bool isQ = bn < C_SZ;
#pragma unroll
  for (int mq = 0; mq < 8; ++mq)
#pragma unroll
    for (int nq = 0; nq < 4; ++nq) {
      const int col = bn + wn * 64 + nq * 16 + l16;
      const int hh = (col >> 6) & 15, d = col & 63;
#pragma unroll
      for (int r = 0; r < 4; ++r) {
        const int row = bm + wm * 128 + mq * 16 + quad * 4 + r;
        const int bb_ = row >> 11, t = row & 2047;
        const size_t idx = ((size_t)(bb_ * 16 + hh) * T_SZ + t) * HD_SZ + d;
        const float val = acc[mq][nq][r] + bv[nq];
        if (isQ) qR[idx] = __float2bfloat16(val * Q_PRESCALE);
        else     kR[idx] = __float2bfloat16(val);
      }
    }
}

// 128x128 tile, 4 waves. MODE 0: V cols -> vT [bh][d][t]; MODE 1: proj -> fp32.
template <int MODE>
__global__ __launch_bounds__(256, 3) void gemm_tri128(
    const __hip_bfloat16* __restrict__ A, const __hip_bfloat16* __restrict__ Bt,
    const float* __restrict__ bias, float* __restrict__ Cf,
    __hip_bfloat16* __restrict__ vT) {
  __shared__ __align__(16) __hip_bfloat16 sA[3][128 * 32];  // 24 KiB
  __shared__ __align__(16) __hip_bfloat16 sB[3][128 * 32];  // 24 KiB

  const int tid = threadIdx.x;
  const int wave = tid >> 6, lane = tid & 63;
  const int quad = lane >> 4, l16 = lane & 15;
  const int rw = (wave & 1) * 64, cw = (wave >> 1) * 64;

  const int xcd = (int)blockIdx.x & 7, lb = (int)blockIdx.x >> 3;
  const int bm = (xcd * 8 + (lb >> 3)) * 128;
  const int bn = (lb & 7) * 128;

  const int srow = tid >> 2;  // 0..63
  const int scol = 8 * ((tid & 3) ^ ((tid >> 3) & 3));
  const int sdst = tid * 8;
  const __hip_bfloat16* gA = A + (size_t)(bm + srow) * C_SZ + scol;
  const __hip_bfloat16* gB = Bt + (size_t)(bn + srow) * C_SZ + scol;

  f32x4 acc[4][4];
#pragma unroll
  for (int i = 0; i < 4; ++i)
#pragma unroll
    for (int j = 0; j < 4; ++j) acc[i][j] = (f32x4){0.f, 0.f, 0.f, 0.f};

#define STG128(buf, kt)                                                        \
  do {                                                                         \
    async_ld16(&sA[buf][sdst], gA + (kt) * 32);                                \
    async_ld16(&sA[buf][2048 + sdst], gA + (size_t)64 * C_SZ + (kt) * 32);     \
    async_ld16(&sB[buf][sdst], gB + (kt) * 32);                                \
    async_ld16(&sB[buf][2048 + sdst], gB + (size_t)64 * C_SZ + (kt) * 32);     \
  } while (0)

  STG128(0, 0);
  STG128(1, 1);
  asm volatile("s_waitcnt vmcnt(4)" ::: "memory");
  bar();

  constexpr int NT = C_SZ / 32;  // 32
  int cur = 0;
  for (int kt = 0; kt < NT; ++kt) {
    const int stg = cur == 0 ? 2 : cur - 1;
    if (kt + 2 < NT) STG128(stg, kt + 2);

    const __hip_bfloat16* ab = sA[cur];
    const __hip_bfloat16* bb = sB[cur];
    bf16x8 af[4], bfr[4];
#pragma unroll
    for (int mq = 0; mq < 4; ++mq) af[mq] = frag32(ab, rw + mq * 16 + l16, quad);
#pragma unroll
    for (int nq = 0; nq < 4; ++nq) bfr[nq] = frag32(bb, cw + nq * 16 + l16, quad);
#pragma unroll
    for (int mq = 0; mq < 4; ++mq)
#pragma unroll
      for (int nq = 0; nq < 4; ++nq)
        acc[mq][nq] = __builtin_amdgcn_mfma_f32_16x16x32_bf16(af[mq], bfr[nq], acc[mq][nq], 0, 0, 0);

    if (kt + 1 < NT) {
      if (kt + 2 < NT) asm volatile("s_waitcnt vmcnt(4)" ::: "memory");
      else             asm volatile("s_waitcnt vmcnt(0)" ::: "memory");
      bar();
    }
    cur = cur == 2 ? 0 : cur + 1;
  }
#undef STG128

  float bv[4];
#pragma unroll
  for (int nq = 0; nq < 4; ++nq) bv[nq] = bias[bn + cw + nq * 16 + l16];
#pragma unroll
  for (int mq = 0; mq < 4; ++mq)
#pragma unroll
    for (int nq = 0; nq < 4; ++nq) {
      const int col = bn + cw + nq * 16 + l16;  // 0..1023 local
#pragma unroll
      for (int r = 0; r < 4; ++r) {
        const int row = bm + rw + mq * 16 + quad * 4 + r;
        const float val = acc[mq][nq][r] + bv[nq];
        if (MODE == 0) {
          const int bb_ = row >> 11, t = row & 2047;
          const int hh = col >> 6, d = col & 63;
          vT[((size_t)(bb_ * 16 + hh) * HD_SZ + d) * T_SZ + t] = __float2bfloat16(val);
        } else {
          Cf[(size_t)row * C_SZ + col] = val;
        }
      }
    }
}

// ---------------------------------------------------------------------------
// MFMA causal flash attention, r6: 128 q-rows/block, 32 q-rows/wave
// (2 groups of 16). K/V LDS fragments read ONCE per chunk and reused by
// both q-groups -> LDS-pipe traffic per MFMA halved (kernel was
// LDS-pipe-bound: reads+bpermute+writes ~1450 cyc/chunk vs 310 MFMA).
// Swapped QK^T + in-register 8-shfl P exchange per group (verified r4/r5).
// ---------------------------------------------------------------------------
#define ATT_ST 72

// 8-shfl quad exchange (verified r4): input s[4] = this group's P row
// (keys 16*sub + 4*quad + r), output A0/A1 = PV A-frags (keys quad*8+j,
// 32+quad*8+j).
__device__ __forceinline__ void p_exchange(
    const f32x4& s0, const f32x4& s1, const f32x4& s2, const f32x4& s3,
    bool uSel, bool cSel, int srcE, int srcO, bf16x8& A0v, bf16x8& A1v) {
  uint32_t pk[4][2];
  pk[0][0] = pk2(s0[0], s0[1]); pk[0][1] = pk2(s0[2], s0[3]);
  pk[1][0] = pk2(s1[0], s1[1]); pk[1][1] = pk2(s1[2], s1[3]);
  pk[2][0] = pk2(s2[0], s2[1]); pk[2][1] = pk2(s2[2], s2[3]);
  pk[3][0] = pk2(s3[0], s3[1]); pk[3][1] = pk2(s3[2], s3[3]);

  uint32_t g0 = (uint32_t)__shfl((int)(uSel ? pk[1][0] : pk[0][0]), srcE, 64);
  uint32_t g1 = (uint32_t)__shfl((int)(uSel ? pk[0][0] : pk[1][0]), srcO, 64);
  uint32_t g2 = (uint32_t)__shfl((int)(uSel ? pk[3][0] : pk[2][0]), srcE, 64);
  uint32_t g3 = (uint32_t)__shfl((int)(uSel ? pk[2][0] : pk[3][0]), srcO, 64);
  uint32_t g4 = (uint32_t)__shfl((int)(uSel ? pk[1][1] : pk[0][1]), srcE, 64);
  uint32_t g5 = (uint32_t)__shfl((int)(uSel ? pk[0][1] : pk[1][1]), srcO, 64);
  uint32_t g6 = (uint32_t)__shfl((int)(uSel ? pk[3][1] : pk[2][1]), srcE, 64);
  uint32_t g7 = (uint32_t)__shfl((int)(uSel ? pk[2][1] : pk[3][1]), srcO, 64);

  union PU { uint32_t d[4]; bf16x8 v; } A0, A1;
  A0.d[0] = cSel ? g1 : g0;  A0.d[1] = cSel ? g5 : g4;
  A0.d[2] = cSel ? g0 : g1;  A0.d[3] = cSel ? g4 : g5;
  A1.d[0] = cSel ? g3 : g2;  A1.d[1] = cSel ? g7 : g6;
  A1.d[2] = cSel ? g2 : g3;  A1.d[3] = cSel ? g6 : g7;
  A0v = A0.v;
  A1v = A1.v;
}

__global__ __launch_bounds__(256, 3) void attn_mfma_kernel(
    const __hip_bfloat16* __restrict__ qR, const __hip_bfloat16* __restrict__ kR,
    const __hip_bfloat16* __restrict__ vT, __hip_bfloat16* __restrict__ y) {
  __shared__ __align__(16) __hip_bfloat16 sQ[128][ATT_ST];
  __shared__ __align__(16) __hip_bfloat16 sK[64][ATT_ST];
  __shared__ __align__(16) __hip_bfloat16 sVt[64][ATT_ST];  // [dim][key]

  const int bh = blockIdx.x;                         // XCD = bh%8 (heuristic)
  const int tile = (int)gridDim.y - 1 - blockIdx.y;  // longest-first
  const int t0 = tile * 128;
  const int tid = threadIdx.x;
  const int wave = tid >> 6, lane = tid & 63;
  const int quad = lane >> 4, l16 = lane & 15;
  const int wrowQ = wave * 32;  // wave's 32-row base within the q-tile

  const __hip_bfloat16* qb = qR + (size_t)bh * T_SZ * HD_SZ;
  const __hip_bfloat16* kb = kR + (size_t)bh * T_SZ * HD_SZ;
  const __hip_bfloat16* vb = vT + (size_t)bh * HD_SZ * T_SZ;

  const int sr = tid >> 2, sc = (tid & 3) * 16;  // 16 elems/thread per 4K tile

  // exchange constants (verified r4)
  const bool uSel = (quad & 1) != 0;
  const bool cSel = (quad >> 1) != 0;
  const int srcE = l16 + 32 * (quad & 1) + 16 * (quad >> 1);
  const int srcO = srcE ^ 16;

  // ---- stage Q (contiguous 16 KB, 4 float4/thread) ----
  {
    const __hip_bfloat16* src = qb + (size_t)t0 * HD_SZ + tid * 16;
    *(float4*)&sQ[sr][sc] = *(const float4*)src;
    *(float4*)&sQ[sr][sc + 8] = *(const float4*)(src + 8);
    const __hip_bfloat16* src2 = src + 64 * HD_SZ;
    *(float4*)&sQ[64 + sr][sc] = *(const float4*)src2;
    *(float4*)&sQ[64 + sr][sc + 8] = *(const float4*)(src2 + 8);
  }

  // ---- preload chunk 0 K/V into regs (coalesced) ----
  float4 krg0, krg1, vrg0, vrg1;
  {
    const __hip_bfloat16* ks = kb + tid * 16;  // j0 = 0
    krg0 = *(const float4*)ks;
    krg1 = *(const float4*)(ks + 8);
    const __hip_bfloat16* vs = vb + (size_t)sr * T_SZ + sc;  // row d, cols t
    vrg0 = *(const float4*)vs;
    vrg1 = *(const float4*)(vs + 8);
  }

  __syncthreads();  // Q visible
  bf16x8 qa[2][2];
#pragma unroll
  for (int g = 0; g < 2; ++g) {
    qa[g][0] = *(const bf16x8*)&sQ[wrowQ + g * 16 + l16][quad * 8];
    qa[g][1] = *(const bf16x8*)&sQ[wrowQ + g * 16 + l16][32 + quad * 8];
  }

  float lacc0 = 0.f, lacc1 = 0.f;  // per-group row-sum partials
  f32x4 o[2][4];
#pragma unroll
  for (int g = 0; g < 2; ++g)
#pragma unroll
    for (int nn = 0; nn < 4; ++nn) o[g][nn] = (f32x4){0.f, 0.f, 0.f, 0.f};

  const int jmax = t0 + 64;  // last chunk start (keys up to t0+127)
  for (int j0 = 0; j0 <= jmax; j0 += 64) {
    // ---- drain prefetch regs -> LDS ----
    *(float4*)&sK[sr][sc] = krg0;
    *(float4*)&sK[sr][sc + 8] = krg1;
    *(float4*)&sVt[sr][sc] = vrg0;
    *(float4*)&sVt[sr][sc + 8] = vrg1;
    // ---- issue next chunk's loads (overlap with compute below) ----
    if (j0 + 64 <= jmax) {
      const __hip_bfloat16* ks = kb + (size_t)(j0 + 64) * HD_SZ + tid * 16;
      krg0 = *(const float4*)ks;
      krg1 = *(const float4*)(ks + 8);
      const __hip_bfloat16* vs = vb + (size_t)sr * T_SZ + j0 + 64 + sc;
      vrg0 = *(const float4*)vs;
      vrg1 = *(const float4*)(vs + 8);
    }
    __syncthreads();  // K/V visible

    // ---- S^T = K.Q^T for both q-groups; K-frags read ONCE ----
    f32x4 s0[4], s1[4];
    __builtin_amdgcn_s_setprio(1);
#pragma unroll
    for (int sub = 0; sub < 4; ++sub) {
      bf16x8 kf0 = *(const bf16x8*)&sK[sub * 16 + l16][quad * 8];
      bf16x8 kf1 = *(const bf16x8*)&sK[sub * 16 + l16][32 + quad * 8];
      s0[sub] = (f32x4){0.f, 0.f, 0.f, 0.f};
      s0[sub] = __builtin_amdgcn_mfma_f32_16x16x32_bf16(kf0, qa[0][0], s0[sub], 0, 0, 0);
      s0[sub] = __builtin_amdgcn_mfma_f32_16x16x32_bf16(kf1, qa[0][1], s0[sub], 0, 0, 0);
      s1[sub] = (f32x4){0.f, 0.f, 0.f, 0.f};
      s1[sub] = __builtin_amdgcn_mfma_f32_16x16x32_bf16(kf0, qa[1][0], s1[sub], 0, 0, 0);
      s1[sub] = __builtin_amdgcn_mfma_f32_16x16x32_bf16(kf1, qa[1][1], s1[sub], 0, 0, 0);
    }
    __builtin_amdgcn_s_setprio(0);

    // ---- causal mask (chunks overlapping the diagonal only) ----
    {
      const int qb0 = t0 + wrowQ;  // group-0 min row
      if (j0 + 63 > qb0) {
        const int qrow = qb0 + l16;
#pragma unroll
        for (int sub = 0; sub < 4; ++sub)
#pragma unroll
          for (int r = 0; r < 4; ++r)
            if (j0 + sub * 16 + quad * 4 + r > qrow) s0[sub][r] = -1e30f;
      }
      const int qb1 = qb0 + 16;    // group-1 min row
      if (j0 + 63 > qb1) {
        const int qrow = qb1 + l16;
#pragma unroll
        for (int sub = 0; sub < 4; ++sub)
#pragma unroll
          for (int r = 0; r < 4; ++r)
            if (j0 + sub * 16 + quad * 4 + r > qrow) s1[sub][r] = -1e30f;
      }
    }

    // ---- p = exp2(s) (scale pre-folded); per-group row-sum partials ----
#pragma unroll
    for (int sub = 0; sub < 4; ++sub)
#pragma unroll
      for (int r = 0; r < 4; ++r) {
        s0[sub][r] = __builtin_amdgcn_exp2f(s0[sub][r]);
        s1[sub][r] = __builtin_amdgcn_exp2f(s1[sub][r]);
      }
#pragma unroll
    for (int sub = 0; sub < 4; ++sub) {
      lacc0 += (s0[sub][0] + s0[sub][1]) + (s0[sub][2] + s0[sub][3]);
      lacc1 += (s1[sub][0] + s1[sub][1]) + (s1[sub][2] + s1[sub][3]);
    }

    // ---- pack + exchange per group -> PV A-frags ----
    bf16x8 A0g0, A1g0, A0g1, A1g1;
    p_exchange(s0[0], s0[1], s0[2], s0[3], uSel, cSel, srcE, srcO, A0g0, A1g0);
    p_exchange(s1[0], s1[1], s1[2], s1[3], uSel, cSel, srcE, srcO, A0g1, A1g1);

    // ---- O += P.V for both groups; V-frags read ONCE ----
    __builtin_amdgcn_s_setprio(1);
#pragma unroll
    for (int nn = 0; nn < 4; ++nn) {
      bf16x8 vf0 = *(const bf16x8*)&sVt[nn * 16 + l16][quad * 8];
      bf16x8 vf1 = *(const bf16x8*)&sVt[nn * 16 + l16][32 + quad * 8];
      o[0][nn] = __builtin_amdgcn_mfma_f32_16x16x32_bf16(A0g0, vf0, o[0][nn], 0, 0, 0);
      o[0][nn] = __builtin_amdgcn_mfma_f32_16x16x32_bf16(A1g0, vf1, o[0][nn], 0, 0, 0);
      o[1][nn] = __builtin_amdgcn_mfma_f32_16x16x32_bf16(A0g1, vf0, o[1][nn], 0, 0, 0);
      o[1][nn] = __builtin_amdgcn_mfma_f32_16x16x32_bf16(A1g1, vf1, o[1][nn], 0, 0, 0);
    }
    __builtin_amdgcn_s_setprio(0);

    if (j0 < jmax) __syncthreads();  // readers done before next overwrite
  }

  // ---- final row-sum reduction + epilogue ----
  lacc0 += __shfl_xor(lacc0, 16);
  lacc0 += __shfl_xor(lacc0, 32);
  lacc1 += __shfl_xor(lacc1, 16);
  lacc1 += __shfl_xor(lacc1, 32);
  // o[g][nn][r] belongs to q_local = quad*4+r; its row-sum is at l16' = quad*4+r
  float inv[2][4];
#pragma unroll
  for (int r = 0; r < 4; ++r) {
    inv[0][r] = 1.0f / __shfl(lacc0, (lane & 48) + quad * 4 + r, 64);
    inv[1][r] = 1.0f / __shfl(lacc1, (lane & 48) + quad * 4 + r, 64);
  }

  const int b = bh >> 4, h = bh & 15;
#pragma unroll
  for (int g = 0; g < 2; ++g)
#pragma unroll
    for (int nn = 0; nn < 4; ++nn)
#pragma unroll
      for (int r = 0; r < 4; ++r) {
        const int t = t0 + wrowQ + g * 16 + quad * 4 + r;
        y[((size_t)b * T_SZ + t) * C_SZ + h * HD_SZ + nn * 16 + l16] =
            __float2bfloat16(o[g][nn][r] * inv[g][r]);
      }
}

// ---------------------------------------------------------------------------
extern "C" void kernel_launch(void* const* d_in, const int* in_sizes, int n_in,
                              void* d_out, int out_size, void* d_ws, size_t ws_size,
                              hipStream_t stream) {
  const float* x      = (const float*)d_in[0];  // [8192,1024] fp32
  const float* w_attn = (const float*)d_in[1];  // [1024,3072] fp32
  const float* b_attn = (const float*)d_in[2];  // [3072] fp32
  const float* w_proj = (const float*)d_in[3];  // [1024,1024] fp32
  const float* b_proj = (const float*)d_in[4];  // [1024] fp32
  float* out = (float*)d_out;                   // [8192,1024] fp32

  // ws layout (75.5 MB): xb | waT | wpT | qR | kR | vT ; yb aliases xb.
  __hip_bfloat16* xb  = (__hip_bfloat16*)d_ws;                    // 16.78 MB
  __hip_bfloat16* waT = xb + (size_t)M_SZ * C_SZ;                 //  6.29 MB
  __hip_bfloat16* wpT = waT + (size_t)3 * C_SZ * C_SZ;            //  2.10 MB
  __hip_bfloat16* qR  = wpT + (size_t)C_SZ * C_SZ;                // 16.78 MB
  __hip_bfloat16* kR  = qR + (size_t)M_SZ * C_SZ;                 // 16.78 MB
  __hip_bfloat16* vT  = kR + (size_t)M_SZ * C_SZ;                 // 16.78 MB
  __hip_bfloat16* yb  = xb;  // xb dead after QKV GEMMs

  conv_bf16_kernel<<<(M_SZ * C_SZ) / (256 * 4), 256, 0, stream>>>(x, xb);
  transpose_conv_kernel<C_SZ, 3 * C_SZ><<<dim3(96, 32), 256, 0, stream>>>(w_attn, waT);
  transpose_conv_kernel<C_SZ, C_SZ><<<dim3(32, 32), 256, 0, stream>>>(w_proj, wpT);

  // 1a) Q+K projection: 256^2 triple-buffer, grid 256 = 1 exact round.
  gemm_tri256_qk<<<dim3(256), 512, 0, stream>>>(xb, waT, b_attn, qR, kR);

  // 1b) V projection: 128^2 triple-buffer, 3 blk/CU, grid 512 co-resident.
  gemm_tri128<0><<<dim3(512), 256, 0, stream>>>(
      xb, waT + (size_t)2 * C_SZ * C_SZ, b_attn + 2 * C_SZ, nullptr, vT);

  // 2) causal flash attention: 128 q-rows/block, 16 tiles, longest-first.
  attn_mfma_kernel<<<dim3(B_SZ * NH_SZ, T_SZ / 128), 256, 0, stream>>>(qR, kR, vT, yb);

  // 3) output projection -> fp32 out
  gemm_tri128<1><<<dim3(512), 256, 0, stream>>>(
      (const __hip_bfloat16*)yb, wpT, b_proj, out, nullptr);
}

// Round 7
// 242.421 us; speedup vs baseline: 1.0716x; 1.0305x over previous
//
#include <hip/hip_runtime.h>
#include <hip/hip_bf16.h>

// Problem constants (B=4, T=2048, C=1024, NH=16, HD=64)
// fp32 in, fp32 out, bf16 MFMA compute internally.
#define B_SZ 4
#define T_SZ 2048
#define C_SZ 1024
#define NH_SZ 16
#define HD_SZ 64
#define M_SZ (B_SZ * T_SZ)  // 8192 rows

typedef __bf16 bf16x8 __attribute__((ext_vector_type(8)));
typedef __bf16 bf16x4 __attribute__((ext_vector_type(4)));
typedef float f32x4 __attribute__((ext_vector_type(4)));

// async global->LDS, 16B per lane. LDS dest is wave-uniform base + lane*16.
__device__ __forceinline__ void async_ld16(__hip_bfloat16* lds, const __hip_bfloat16* g) {
  __builtin_amdgcn_global_load_lds(
      (const __attribute__((address_space(1))) void*)g,
      (__attribute__((address_space(3))) void*)lds, 16, 0, 0);
}

// raw block barrier; compiler memory fences on both sides, no forced drain.
__device__ __forceinline__ void bar() {
  asm volatile("" ::: "memory");
  __builtin_amdgcn_s_barrier();
  asm volatile("" ::: "memory");
}

// Swizzled LDS fragment read for 64B rows (BK=32):
// physical byte = 64*row + 16*(quad ^ ((row>>1)&3)).
__device__ __forceinline__ bf16x8 frag32(const __hip_bfloat16* base, int row, int q) {
  const int byte = (row << 6) + (((q ^ (row >> 1)) & 3) << 4);
  return *(const bf16x8*)((const char*)base + byte);
}

// Attention LDS swizzle: 128B rows (64 bf16), 16B slot XOR'd with row&7
// (m214 recipe). Both writes and reads use SWZ -> consistent, conflict-free
// (every consecutive-8-lane group hits 8 distinct 16B slots).
#define SWZ(row, cb) (((row) << 7) + ((cb) ^ (((row) & 7) << 4)))

// pack two f32 -> dword of 2 bf16 (lo = first arg), hardware RNE cvt.
__device__ __forceinline__ uint32_t pk2(float lo, float hi) {
  uint32_t r;
  asm("v_cvt_pk_bf16_f32 %0, %1, %2" : "=v"(r) : "v"(lo), "v"(hi));
  return r;
}

// ---------------------------------------------------------------------------
// Pre-pass 1: fp32 -> bf16 copy (x -> xb).
// ---------------------------------------------------------------------------
__global__ __launch_bounds__(256) void conv_bf16_kernel(
    const float* __restrict__ X, __hip_bfloat16* __restrict__ Y) {
  const int i = (blockIdx.x * 256 + threadIdx.x) * 4;
  float4 v = *(const float4*)&X[i];
  union { bf16x4 v; __hip_bfloat16 h[4]; } o;
  o.h[0] = __float2bfloat16(v.x); o.h[1] = __float2bfloat16(v.y);
  o.h[2] = __float2bfloat16(v.z); o.h[3] = __float2bfloat16(v.w);
  *(bf16x4*)&Y[i] = o.v;
}

// ---------------------------------------------------------------------------
// Pre-pass 2: Wt[n][k] = bf16(W[k][n]); W is [KD][ND] fp32. 32x32 LDS tiles.
// ---------------------------------------------------------------------------
template <int KD, int ND>
__global__ __launch_bounds__(256) void transpose_conv_kernel(
    const float* __restrict__ W, __hip_bfloat16* __restrict__ Wt) {
  __shared__ float sT[32][33];
  const int n0 = blockIdx.x * 32, k0 = blockIdx.y * 32;
  const int tid = threadIdx.x;
  {
    const int r = tid >> 3, c = (tid & 7) * 4;
    float4 v = *(const float4*)&W[(size_t)(k0 + r) * ND + n0 + c];
    sT[r][c] = v.x; sT[r][c + 1] = v.y; sT[r][c + 2] = v.z; sT[r][c + 3] = v.w;
  }
  __syncthreads();
  {
    const int n = tid >> 3, kq = (tid & 7) * 4;
    union { bf16x4 v; __hip_bfloat16 h[4]; } o;
#pragma unroll
    for (int j = 0; j < 4; ++j) o.h[j] = __float2bfloat16(sT[kq + j][n]);
    *(bf16x4*)&Wt[(size_t)(n0 + n) * KD + k0 + kq] = o.v;
  }
}

// ---------------------------------------------------------------------------
// Triple-buffered, never-drain GEMM kernels (BK=32). Ring invariant
// (verified r3-r6): entering tile kt, buf[cur] landed, tile kt+1 in flight;
// stage kt+2 (WAR-safe: its buffer's readers finished 2 barriers ago),
// compute kt, counted vmcnt (kt+1 only), one barrier.
// ---------------------------------------------------------------------------

// Q scale folds softmax 1/sqrt(64) AND log2(e) so attention can use exp2.
#define Q_PRESCALE 0.18033688011112042f

// Q+K projection: 256x128 tile, 8 waves (4Mx2N, wave = 64x64, acc[4][4]).
// LDS 72 KiB -> 2 blocks/CU; grid 512 = exactly co-resident (TLP: one
// block's stalls hide under the other). N=2048 columns of w_attn.
__global__ __launch_bounds__(512, 4) void gemm_qk_ring(
    const __hip_bfloat16* __restrict__ A, const __hip_bfloat16* __restrict__ Bt,
    const float* __restrict__ bias,
    __hip_bfloat16* __restrict__ qR, __hip_bfloat16* __restrict__ kR) {
  __shared__ __align__(16) __hip_bfloat16 sA[3][256 * 32];  // 48 KiB
  __shared__ __align__(16) __hip_bfloat16 sB[3][128 * 32];  // 24 KiB

  const int tid = threadIdx.x;
  const int wave = tid >> 6, lane = tid & 63;
  const int quad = lane >> 4, l16 = lane & 15;
  const int wm = wave >> 1, wn = wave & 1;  // 4M x 2N, wave out 64x64

  // XCD rectangles: 512 blocks = 8 XCDs x (4m x 16n).
  const int xcd = (int)blockIdx.x & 7, lb = (int)blockIdx.x >> 3;  // lb 0..63
  const int bm = (xcd * 4 + (lb >> 4)) * 256;
  const int bn = (lb & 15) * 128;

  // Staging: per issue 128 rows x 32 cols (8KB); thread -> row tid/4,
  // 16B slot tid&3 (linear LDS), global col inverse-swizzled for frag32.
  const int srow = tid >> 2;  // 0..127
  const int scol = 8 * ((tid & 3) ^ ((tid >> 3) & 3));
  const int sdst = tid * 8;  // elems
  const __hip_bfloat16* gA = A + (size_t)(bm + srow) * C_SZ + scol;
  const __hip_bfloat16* gB = Bt + (size_t)(bn + srow) * C_SZ + scol;

  f32x4 acc[4][4];
#pragma unroll
  for (int i = 0; i < 4; ++i)
#pragma unroll
    for (int j = 0; j < 4; ++j) acc[i][j] = (f32x4){0.f, 0.f, 0.f, 0.f};

#define STGQK(buf, kt)                                                         \
  do {                                                                         \
    async_ld16(&sA[buf][sdst], gA + (kt) * 32);                                \
    async_ld16(&sA[buf][4096 + sdst], gA + (size_t)128 * C_SZ + (kt) * 32);    \
    async_ld16(&sB[buf][sdst], gB + (kt) * 32);                                \
  } while (0)

  STGQK(0, 0);
  STGQK(1, 1);
  asm volatile("s_waitcnt vmcnt(3)" ::: "memory");  // tile 0 landed; 1 in flight
  bar();

  constexpr int NT = C_SZ / 32;  // 32
  int cur = 0;
  for (int kt = 0; kt < NT; ++kt) {
    const int stg = cur == 0 ? 2 : cur - 1;  // (cur+2)%3
    if (kt + 2 < NT) STGQK(stg, kt + 2);

    const __hip_bfloat16* ab = sA[cur];
    const __hip_bfloat16* bb = sB[cur];
    bf16x8 af[4], bfr[4];
#pragma unroll
    for (int mq = 0; mq < 4; ++mq) af[mq] = frag32(ab, wm * 64 + mq * 16 + l16, quad);
#pragma unroll
    for (int nq = 0; nq < 4; ++nq) bfr[nq] = frag32(bb, wn * 64 + nq * 16 + l16, quad);
#pragma unroll
    for (int mq = 0; mq < 4; ++mq)
#pragma unroll
      for (int nq = 0; nq < 4; ++nq)
        acc[mq][nq] = __builtin_amdgcn_mfma_f32_16x16x32_bf16(af[mq], bfr[nq], acc[mq][nq], 0, 0, 0);

    if (kt + 1 < NT) {
      if (kt + 2 < NT) asm volatile("s_waitcnt vmcnt(3)" ::: "memory");
      else             asm volatile("s_waitcnt vmcnt(0)" ::: "memory");
      bar();
    }
    cur = cur == 2 ? 0 : cur + 1;
  }
#undef STGQK

  // Epilogue: Q (cols<1024, x Q_PRESCALE) / K split; both [bh][t][d].
  float bv[4];
#pragma unroll
  for (int nq = 0; nq < 4; ++nq) bv[nq] = bias[bn + wn * 64 + nq * 16 + l16];
  const bool isQ = bn < C_SZ;
#pragma unroll
  for (int mq = 0; mq < 4; ++mq)
#pragma unroll
    for (int nq = 0; nq < 4; ++nq) {
      const int col = bn + wn * 64 + nq * 16 + l16;
      const int hh = (col >> 6) & 15, d = col & 63;
#pragma unroll
      for (int r = 0; r < 4; ++r) {
        const int row = bm + wm * 64 + mq * 16 + quad * 4 + r;
        const int bb_ = row >> 11, t = row & 2047;
        const size_t idx = ((size_t)(bb_ * 16 + hh) * T_SZ + t) * HD_SZ + d;
        const float val = acc[mq][nq][r] + bv[nq];
        if (isQ) qR[idx] = __float2bfloat16(val * Q_PRESCALE);
        else     kR[idx] = __float2bfloat16(val);
      }
    }
}

// 128x128 tile, 4 waves. MODE 0: V cols -> vT [bh][d][t]; MODE 1: proj -> fp32.
template <int MODE>
__global__ __launch_bounds__(256, 3) void gemm_tri128(
    const __hip_bfloat16* __restrict__ A, const __hip_bfloat16* __restrict__ Bt,
    const float* __restrict__ bias, float* __restrict__ Cf,
    __hip_bfloat16* __restrict__ vT) {
  __shared__ __align__(16) __hip_bfloat16 sA[3][128 * 32];  // 24 KiB
  __shared__ __align__(16) __hip_bfloat16 sB[3][128 * 32];  // 24 KiB

  const int tid = threadIdx.x;
  const int wave = tid >> 6, lane = tid & 63;
  const int quad = lane >> 4, l16 = lane & 15;
  const int rw = (wave & 1) * 64, cw = (wave >> 1) * 64;

  const int xcd = (int)blockIdx.x & 7, lb = (int)blockIdx.x >> 3;
  const int bm = (xcd * 8 + (lb >> 3)) * 128;
  const int bn = (lb & 7) * 128;

  const int srow = tid >> 2;  // 0..63
  const int scol = 8 * ((tid & 3) ^ ((tid >> 3) & 3));
  const int sdst = tid * 8;
  const __hip_bfloat16* gA = A + (size_t)(bm + srow) * C_SZ + scol;
  const __hip_bfloat16* gB = Bt + (size_t)(bn + srow) * C_SZ + scol;

  f32x4 acc[4][4];
#pragma unroll
  for (int i = 0; i < 4; ++i)
#pragma unroll
    for (int j = 0; j < 4; ++j) acc[i][j] = (f32x4){0.f, 0.f, 0.f, 0.f};

#define STG128(buf, kt)                                                        \
  do {                                                                         \
    async_ld16(&sA[buf][sdst], gA + (kt) * 32);                                \
    async_ld16(&sA[buf][2048 + sdst], gA + (size_t)64 * C_SZ + (kt) * 32);     \
    async_ld16(&sB[buf][sdst], gB + (kt) * 32);                                \
    async_ld16(&sB[buf][2048 + sdst], gB + (size_t)64 * C_SZ + (kt) * 32);     \
  } while (0)

  STG128(0, 0);
  STG128(1, 1);
  asm volatile("s_waitcnt vmcnt(4)" ::: "memory");
  bar();

  constexpr int NT = C_SZ / 32;  // 32
  int cur = 0;
  for (int kt = 0; kt < NT; ++kt) {
    const int stg = cur == 0 ? 2 : cur - 1;
    if (kt + 2 < NT) STG128(stg, kt + 2);

    const __hip_bfloat16* ab = sA[cur];
    const __hip_bfloat16* bb = sB[cur];
    bf16x8 af[4], bfr[4];
#pragma unroll
    for (int mq = 0; mq < 4; ++mq) af[mq] = frag32(ab, rw + mq * 16 + l16, quad);
#pragma unroll
    for (int nq = 0; nq < 4; ++nq) bfr[nq] = frag32(bb, cw + nq * 16 + l16, quad);
#pragma unroll
    for (int mq = 0; mq < 4; ++mq)
#pragma unroll
      for (int nq = 0; nq < 4; ++nq)
        acc[mq][nq] = __builtin_amdgcn_mfma_f32_16x16x32_bf16(af[mq], bfr[nq], acc[mq][nq], 0, 0, 0);

    if (kt + 1 < NT) {
      if (kt + 2 < NT) asm volatile("s_waitcnt vmcnt(4)" ::: "memory");
      else             asm volatile("s_waitcnt vmcnt(0)" ::: "memory");
      bar();
    }
    cur = cur == 2 ? 0 : cur + 1;
  }
#undef STG128

  float bv[4];
#pragma unroll
  for (int nq = 0; nq < 4; ++nq) bv[nq] = bias[bn + cw + nq * 16 + l16];
#pragma unroll
  for (int mq = 0; mq < 4; ++mq)
#pragma unroll
    for (int nq = 0; nq < 4; ++nq) {
      const int col = bn + cw + nq * 16 + l16;  // 0..1023 local
#pragma unroll
      for (int r = 0; r < 4; ++r) {
        const int row = bm + rw + mq * 16 + quad * 4 + r;
        const float val = acc[mq][nq][r] + bv[nq];
        if (MODE == 0) {
          const int bb_ = row >> 11, t = row & 2047;
          const int hh = col >> 6, d = col & 63;
          vT[((size_t)(bb_ * 16 + hh) * HD_SZ + d) * T_SZ + t] = __float2bfloat16(val);
        } else {
          Cf[(size_t)row * C_SZ + col] = val;
        }
      }
    }
}

// ---------------------------------------------------------------------------
// MFMA causal flash attention, r7: r6 structure (128 q-rows/block, 2 groups
// per wave, K/V frags read once) + XOR-swizzled LDS (T2/m214) replacing the
// ATT_ST=72 padding (which left 4-way aliasing -> 388 conflict-cyc/chunk).
// LDS 32 KB.
// ---------------------------------------------------------------------------

// 8-shfl quad exchange (verified r4): input s[4] = this group's P row
// (keys 16*sub + 4*quad + r), output A0/A1 = PV A-frags.
__device__ __forceinline__ void p_exchange(
    const f32x4& s0, const f32x4& s1, const f32x4& s2, const f32x4& s3,
    bool uSel, bool cSel, int srcE, int srcO, bf16x8& A0v, bf16x8& A1v) {
  uint32_t pk[4][2];
  pk[0][0] = pk2(s0[0], s0[1]); pk[0][1] = pk2(s0[2], s0[3]);
  pk[1][0] = pk2(s1[0], s1[1]); pk[1][1] = pk2(s1[2], s1[3]);
  pk[2][0] = pk2(s2[0], s2[1]); pk[2][1] = pk2(s2[2], s2[3]);
  pk[3][0] = pk2(s3[0], s3[1]); pk[3][1] = pk2(s3[2], s3[3]);

  uint32_t g0 = (uint32_t)__shfl((int)(uSel ? pk[1][0] : pk[0][0]), srcE, 64);
  uint32_t g1 = (uint32_t)__shfl((int)(uSel ? pk[0][0] : pk[1][0]), srcO, 64);
  uint32_t g2 = (uint32_t)__shfl((int)(uSel ? pk[3][0] : pk[2][0]), srcE, 64);
  uint32_t g3 = (uint32_t)__shfl((int)(uSel ? pk[2][0] : pk[3][0]), srcO, 64);
  uint32_t g4 = (uint32_t)__shfl((int)(uSel ? pk[1][1] : pk[0][1]), srcE, 64);
  uint32_t g5 = (uint32_t)__shfl((int)(uSel ? pk[0][1] : pk[1][1]), srcO, 64);
  uint32_t g6 = (uint32_t)__shfl((int)(uSel ? pk[3][1] : pk[2][1]), srcE, 64);
  uint32_t g7 = (uint32_t)__shfl((int)(uSel ? pk[2][1] : pk[3][1]), srcO, 64);

  union PU { uint32_t d[4]; bf16x8 v; } A0, A1;
  A0.d[0] = cSel ? g1 : g0;  A0.d[1] = cSel ? g5 : g4;
  A0.d[2] = cSel ? g0 : g1;  A0.d[3] = cSel ? g4 : g5;
  A1.d[0] = cSel ? g3 : g2;  A1.d[1] = cSel ? g7 : g6;
  A1.d[2] = cSel ? g2 : g3;  A1.d[3] = cSel ? g6 : g7;
  A0v = A0.v;
  A1v = A1.v;
}

__global__ __launch_bounds__(256, 3) void attn_mfma_kernel(
    const __hip_bfloat16* __restrict__ qR, const __hip_bfloat16* __restrict__ kR,
    const __hip_bfloat16* __restrict__ vT, __hip_bfloat16* __restrict__ y) {
  __shared__ __align__(16) __hip_bfloat16 sQ[128 * 64];  // 16 KB, swizzled
  __shared__ __align__(16) __hip_bfloat16 sK[64 * 64];   //  8 KB, swizzled
  __shared__ __align__(16) __hip_bfloat16 sVt[64 * 64];  //  8 KB, swizzled

  const int bh = blockIdx.x;                         // XCD = bh%8 (heuristic)
  const int tile = (int)gridDim.y - 1 - blockIdx.y;  // longest-first
  const int t0 = tile * 128;
  const int tid = threadIdx.x;
  const int wave = tid >> 6, lane = tid & 63;
  const int quad = lane >> 4, l16 = lane & 15;
  const int wrowQ = wave * 32;  // wave's 32-row base within the q-tile

  const __hip_bfloat16* qb = qR + (size_t)bh * T_SZ * HD_SZ;
  const __hip_bfloat16* kb = kR + (size_t)bh * T_SZ * HD_SZ;
  const __hip_bfloat16* vb = vT + (size_t)bh * HD_SZ * T_SZ;

  const int sr = tid >> 2;             // stage row (0..63)
  const int cb = 32 * (tid & 3);       // stage logical col byte
  const int scE = (tid & 3) * 16;      // stage logical col elems (global src)

  // exchange constants (verified r4)
  const bool uSel = (quad & 1) != 0;
  const bool cSel = (quad >> 1) != 0;
  const int srcE = l16 + 32 * (quad & 1) + 16 * (quad >> 1);
  const int srcO = srcE ^ 16;

  // ---- stage Q (contiguous 16 KB, swizzled writes) ----
  {
    const __hip_bfloat16* src = qb + (size_t)t0 * HD_SZ + tid * 16;
    *(float4*)((char*)sQ + SWZ(sr, cb)) = *(const float4*)src;
    *(float4*)((char*)sQ + SWZ(sr, cb + 16)) = *(const float4*)(src + 8);
    const __hip_bfloat16* src2 = src + 64 * HD_SZ;
    *(float4*)((char*)sQ + SWZ(64 + sr, cb)) = *(const float4*)src2;
    *(float4*)((char*)sQ + SWZ(64 + sr, cb + 16)) = *(const float4*)(src2 + 8);
  }

  // ---- preload chunk 0 K/V into regs (coalesced) ----
  float4 krg0, krg1, vrg0, vrg1;
  {
    const __hip_bfloat16* ks = kb + tid * 16;  // j0 = 0
    krg0 = *(const float4*)ks;
    krg1 = *(const float4*)(ks + 8);
    const __hip_bfloat16* vs = vb + (size_t)sr * T_SZ + scE;  // row d, cols t
    vrg0 = *(const float4*)vs;
    vrg1 = *(const float4*)(vs + 8);
  }

  __syncthreads();  // Q visible
  bf16x8 qa[2][2];
#pragma unroll
  for (int g = 0; g < 2; ++g) {
    const int qr = wrowQ + g * 16 + l16;
    qa[g][0] = *(const bf16x8*)((const char*)sQ + SWZ(qr, quad * 16));
    qa[g][1] = *(const bf16x8*)((const char*)sQ + SWZ(qr, 64 + quad * 16));
  }

  float lacc0 = 0.f, lacc1 = 0.f;  // per-group row-sum partials
  f32x4 o[2][4];
#pragma unroll
  for (int g = 0; g < 2; ++g)
#pragma unroll
    for (int nn = 0; nn < 4; ++nn) o[g][nn] = (f32x4){0.f, 0.f, 0.f, 0.f};

  const int jmax = t0 + 64;  // last chunk start (keys up to t0+127)
  for (int j0 = 0; j0 <= jmax; j0 += 64) {
    // ---- drain prefetch regs -> LDS (swizzled writes) ----
    *(float4*)((char*)sK + SWZ(sr, cb)) = krg0;
    *(float4*)((char*)sK + SWZ(sr, cb + 16)) = krg1;
    *(float4*)((char*)sVt + SWZ(sr, cb)) = vrg0;
    *(float4*)((char*)sVt + SWZ(sr, cb + 16)) = vrg1;
    // ---- issue next chunk's loads (overlap with compute below) ----
    if (j0 + 64 <= jmax) {
      const __hip_bfloat16* ks = kb + (size_t)(j0 + 64) * HD_SZ + tid * 16;
      krg0 = *(const float4*)ks;
      krg1 = *(const float4*)(ks + 8);
      const __hip_bfloat16* vs = vb + (size_t)sr * T_SZ + j0 + 64 + scE;
      vrg0 = *(const float4*)vs;
      vrg1 = *(const float4*)(vs + 8);
    }
    __syncthreads();  // K/V visible

    // ---- S^T = K.Q^T for both q-groups; K-frags read ONCE ----
    f32x4 s0[4], s1[4];
    __builtin_amdgcn_s_setprio(1);
#pragma unroll
    for (int sub = 0; sub < 4; ++sub) {
      const int kr = sub * 16 + l16;
      bf16x8 kf0 = *(const bf16x8*)((const char*)sK + SWZ(kr, quad * 16));
      bf16x8 kf1 = *(const bf16x8*)((const char*)sK + SWZ(kr, 64 + quad * 16));
      s0[sub] = (f32x4){0.f, 0.f, 0.f, 0.f};
      s0[sub] = __builtin_amdgcn_mfma_f32_16x16x32_bf16(kf0, qa[0][0], s0[sub], 0, 0, 0);
      s0[sub] = __builtin_amdgcn_mfma_f32_16x16x32_bf16(kf1, qa[0][1], s0[sub], 0, 0, 0);
      s1[sub] = (f32x4){0.f, 0.f, 0.f, 0.f};
      s1[sub] = __builtin_amdgcn_mfma_f32_16x16x32_bf16(kf0, qa[1][0], s1[sub], 0, 0, 0);
      s1[sub] = __builtin_amdgcn_mfma_f32_16x16x32_bf16(kf1, qa[1][1], s1[sub], 0, 0, 0);
    }
    __builtin_amdgcn_s_setprio(0);

    // ---- causal mask (chunks overlapping the diagonal only) ----
    {
      const int qb0 = t0 + wrowQ;  // group-0 min row
      if (j0 + 63 > qb0) {
        const int qrow = qb0 + l16;
#pragma unroll
        for (int sub = 0; sub < 4; ++sub)
#pragma unroll
          for (int r = 0; r < 4; ++r)
            if (j0 + sub * 16 + quad * 4 + r > qrow) s0[sub][r] = -1e30f;
      }
      const int qb1 = qb0 + 16;    // group-1 min row
      if (j0 + 63 > qb1) {
        const int qrow = qb1 + l16;
#pragma unroll
        for (int sub = 0; sub < 4; ++sub)
#pragma unroll
          for (int r = 0; r < 4; ++r)
            if (j0 + sub * 16 + quad * 4 + r > qrow) s1[sub][r] = -1e30f;
      }
    }

    // ---- p = exp2(s) (scale pre-folded); per-group row-sum partials ----
#pragma unroll
    for (int sub = 0; sub < 4; ++sub)
#pragma unroll
      for (int r = 0; r < 4; ++r) {
        s0[sub][r] = __builtin_amdgcn_exp2f(s0[sub][r]);
        s1[sub][r] = __builtin_amdgcn_exp2f(s1[sub][r]);
      }
#pragma unroll
    for (int sub = 0; sub < 4; ++sub) {
      lacc0 += (s0[sub][0] + s0[sub][1]) + (s0[sub][2] + s0[sub][3]);
      lacc1 += (s1[sub][0] + s1[sub][1]) + (s1[sub][2] + s1[sub][3]);
    }

    // ---- pack + exchange per group -> PV A-frags ----
    bf16x8 A0g0, A1g0, A0g1, A1g1;
    p_exchange(s0[0], s0[1], s0[2], s0[3], uSel, cSel, srcE, srcO, A0g0, A1g0);
    p_exchange(s1[0], s1[1], s1[2], s1[3], uSel, cSel, srcE, srcO, A0g1, A1g1);

    // ---- O += P.V for both groups; V-frags read ONCE ----
    __builtin_amdgcn_s_setprio(1);
#pragma unroll
    for (int nn = 0; nn < 4; ++nn) {
      const int vr = nn * 16 + l16;
      bf16x8 vf0 = *(const bf16x8*)((const char*)sVt + SWZ(vr, quad * 16));
      bf16x8 vf1 = *(const bf16x8*)((const char*)sVt + SWZ(vr, 64 + quad * 16));
      o[0][nn] = __builtin_amdgcn_mfma_f32_16x16x32_bf16(A0g0, vf0, o[0][nn], 0, 0, 0);
      o[0][nn] = __builtin_amdgcn_mfma_f32_16x16x32_bf16(A1g0, vf1, o[0][nn], 0, 0, 0);
      o[1][nn] = __builtin_amdgcn_mfma_f32_16x16x32_bf16(A0g1, vf0, o[1][nn], 0, 0, 0);
      o[1][nn] = __builtin_amdgcn_mfma_f32_16x16x32_bf16(A1g1, vf1, o[1][nn], 0, 0, 0);
    }
    __builtin_amdgcn_s_setprio(0);

    if (j0 < jmax) __syncthreads();  // readers done before next overwrite
  }

  // ---- final row-sum reduction + epilogue ----
  lacc0 += __shfl_xor(lacc0, 16);
  lacc0 += __shfl_xor(lacc0, 32);
  lacc1 += __shfl_xor(lacc1, 16);
  lacc1 += __shfl_xor(lacc1, 32);
  // o[g][nn][r] belongs to q_local = quad*4+r; its row-sum is at l16' = quad*4+r
  float inv[2][4];
#pragma unroll
  for (int r = 0; r < 4; ++r) {
    inv[0][r] = 1.0f / __shfl(lacc0, (lane & 48) + quad * 4 + r, 64);
    inv[1][r] = 1.0f / __shfl(lacc1, (lane & 48) + quad * 4 + r, 64);
  }

  const int b = bh >> 4, h = bh & 15;
#pragma unroll
  for (int g = 0; g < 2; ++g)
#pragma unroll
    for (int nn = 0; nn < 4; ++nn)
#pragma unroll
      for (int r = 0; r < 4; ++r) {
        const int t = t0 + wrowQ + g * 16 + quad * 4 + r;
        y[((size_t)b * T_SZ + t) * C_SZ + h * HD_SZ + nn * 16 + l16] =
            __float2bfloat16(o[g][nn][r] * inv[g][r]);
      }
}

// ---------------------------------------------------------------------------
extern "C" void kernel_launch(void* const* d_in, const int* in_sizes, int n_in,
                              void* d_out, int out_size, void* d_ws, size_t ws_size,
                              hipStream_t stream) {
  const float* x      = (const float*)d_in[0];  // [8192,1024] fp32
  const float* w_attn = (const float*)d_in[1];  // [1024,3072] fp32
  const float* b_attn = (const float*)d_in[2];  // [3072] fp32
  const float* w_proj = (const float*)d_in[3];  // [1024,1024] fp32
  const float* b_proj = (const float*)d_in[4];  // [1024] fp32
  float* out = (float*)d_out;                   // [8192,1024] fp32

  // ws layout (75.5 MB): xb | waT | wpT | qR | kR | vT ; yb aliases xb.
  __hip_bfloat16* xb  = (__hip_bfloat16*)d_ws;                    // 16.78 MB
  __hip_bfloat16* waT = xb + (size_t)M_SZ * C_SZ;                 //  6.29 MB
  __hip_bfloat16* wpT = waT + (size_t)3 * C_SZ * C_SZ;            //  2.10 MB
  __hip_bfloat16* qR  = wpT + (size_t)C_SZ * C_SZ;                // 16.78 MB
  __hip_bfloat16* kR  = qR + (size_t)M_SZ * C_SZ;                 // 16.78 MB
  __hip_bfloat16* vT  = kR + (size_t)M_SZ * C_SZ;                 // 16.78 MB
  __hip_bfloat16* yb  = xb;  // xb dead after QKV GEMMs

  conv_bf16_kernel<<<(M_SZ * C_SZ) / (256 * 4), 256, 0, stream>>>(x, xb);
  transpose_conv_kernel<C_SZ, 3 * C_SZ><<<dim3(96, 32), 256, 0, stream>>>(w_attn, waT);
  transpose_conv_kernel<C_SZ, C_SZ><<<dim3(32, 32), 256, 0, stream>>>(w_proj, wpT);

  // 1a) Q+K projection: 256x128 ring, 2 blk/CU, grid 512 co-resident.
  gemm_qk_ring<<<dim3(512), 512, 0, stream>>>(xb, waT, b_attn, qR, kR);

  // 1b) V projection: 128^2 triple-buffer, 3 blk/CU, grid 512 co-resident.
  gemm_tri128<0><<<dim3(512), 256, 0, stream>>>(
      xb, waT + (size_t)2 * C_SZ * C_SZ, b_attn + 2 * C_SZ, nullptr, vT);

  // 2) causal flash attention: 128 q-rows/block, 16 tiles, longest-first.
  attn_mfma_kernel<<<dim3(B_SZ * NH_SZ, T_SZ / 128), 256, 0, stream>>>(qR, kR, vT, yb);

  // 3) output projection -> fp32 out
  gemm_tri128<1><<<dim3(512), 256, 0, stream>>>(
      (const __hip_bfloat16*)yb, wpT, b_proj, out, nullptr);
}